// Round 10
// baseline (163.567 us; speedup 1.0000x reference)
//
#include <hip/hip_runtime.h>
#include <hip/hip_bf16.h>

// S=64, C=27. DOTLEN = 8640 floats = 2160 float4/row; state = 320; comb = 640; hidden = 64.
// Champion structure: standalone k1 gemv (R5, untouched) + algebraic tail:
//   ns1 never materialized. agg0 = y0 + M@h1 + b0, where
//   y0[r]   = sum_i W0[r][i]*(states1+b2)[i]          (input-only)
//   M[r][n*64+k] = sum_j W0[r][n*320+j]*W2[n][j][k]   (input-only)
//   h1 = relu(W1 @ [states1, agg1] + b1)              (needs agg1)
// M/y0 computed as extra blocks inside K2's dispatch (small-kernel codegen,
// never sharing a kernel with the register-hungry gemv loop -- R7/R9 lesson).

__device__ __forceinline__ float wave_reduce_sum(float v) {
    v += __shfl_xor(v, 32, 64);
    v += __shfl_xor(v, 16, 64);
    v += __shfl_xor(v, 8, 64);
    v += __shfl_xor(v, 4, 64);
    v += __shfl_xor(v, 2, 64);
    v += __shfl_xor(v, 1, 64);
    return v;
}

__device__ __forceinline__ float fma4s(float4 w, float4 x, float acc) {
    acc = fmaf(w.x, x.x, acc);
    acc = fmaf(w.y, x.y, acc);
    acc = fmaf(w.z, x.z, acc);
    acc = fmaf(w.w, x.w, acc);
    return acc;
}

__device__ __forceinline__ float4 add4(float4 a, float4 b) {
    return make_float4(a.x + b.x, a.y + b.y, a.z + b.z, a.w + b.w);
}

// ---------------------------------------------------------------------------
// k1: agg1[8640] = agg_W1 . states2 + agg_b1. (R5 structure, BYTE-IDENTICAL)
__global__ void __launch_bounds__(256) k1_gemv(
    const float* __restrict__ W,     // [8640][8640] block-diag rows
    const float* __restrict__ x,     // [27][8640]
    const float* __restrict__ bias,  // [8640]
    float*       __restrict__ y)     // [8640]
{
    const int b    = blockIdx.x;
    const int node = b / 40;
    const int row0 = node * 320 + (b % 40) * 8;
    const int tid  = threadIdx.x;

    const float4* __restrict__ xf = reinterpret_cast<const float4*>(x) + (size_t)node * 2160;
    const float4* wp[8];
    #pragma unroll
    for (int r = 0; r < 8; ++r)
        wp[r] = reinterpret_cast<const float4*>(W) + (size_t)(row0 + r) * 2160;

    float4 acc[8];
    #pragma unroll
    for (int r = 0; r < 8; ++r) acc[r] = make_float4(0.f, 0.f, 0.f, 0.f);

    for (int j = tid; j < 2160; j += 256) {
        float4 xv = xf[j];
        #pragma unroll
        for (int r = 0; r < 8; ++r) {
            float4 w = wp[r][j];
            acc[r].x = fmaf(w.x, xv.x, acc[r].x);
            acc[r].y = fmaf(w.y, xv.y, acc[r].y);
            acc[r].z = fmaf(w.z, xv.z, acc[r].z);
            acc[r].w = fmaf(w.w, xv.w, acc[r].w);
        }
    }

    float s[8];
    #pragma unroll
    for (int r = 0; r < 8; ++r) {
        s[r] = (acc[r].x + acc[r].y) + (acc[r].z + acc[r].w);
        s[r] = wave_reduce_sum(s[r]);
    }

    __shared__ float red[4][8];
    const int wv = tid >> 6, lane = tid & 63;
    if (lane == 0) {
        #pragma unroll
        for (int r = 0; r < 8; ++r) red[wv][r] = s[r];
    }
    __syncthreads();
    if (tid < 8) {
        float v = red[0][tid] + red[1][tid] + red[2][tid] + red[3][tid];
        y[row0 + tid] = v + bias[row0 + tid];
    }
}

// ---------------------------------------------------------------------------
// K2: 432 h1-blocks + 270 M/y0-blocks (all small, latency-tolerant).
__global__ void __launch_bounds__(256) K2(
    const float* __restrict__ states1,  // [27][320]
    const float* __restrict__ agg1,     // ws [8640]
    const float* __restrict__ W1,       // up_W1_1 [27][64][640]
    const float* __restrict__ b1,       // [27][64]
    const float* __restrict__ W2,       // up_W2_1 [27][320][64]
    const float* __restrict__ b2,       // up_b2_1 flat [8640]
    const float* __restrict__ aggW0,    // [320][8640]
    float* __restrict__ h1,             // ws [1728]
    float* __restrict__ y0p,            // ws [27][320]
    float* __restrict__ M)              // ws [320][1728]
{
    __shared__ __align__(16) float sh[640];
    const int b   = blockIdx.x;
    const int tid = threadIdx.x;
    const int wv  = tid >> 6, lane = tid & 63;

    if (b < 432) {
        // ---- h1[n][k] = relu(W1[n][k,:] @ [states1[n], agg1[n]] + b1[n][k]) ----
        const int n = b >> 4;
        float4* shf = reinterpret_cast<float4*>(sh);
        const float4* __restrict__ s1f = reinterpret_cast<const float4*>(states1) + (size_t)n * 80;
        const float4* __restrict__ a1f = reinterpret_cast<const float4*>(agg1) + (size_t)n * 80;
        if (tid < 80)       shf[tid] = s1f[tid];
        else if (tid < 160) shf[tid] = a1f[tid - 80];
        __syncthreads();

        const int k = (b & 15) * 4 + wv;
        const float4* __restrict__ Wf = reinterpret_cast<const float4*>(W1) + ((size_t)n * 64 + k) * 160;
        float acc = 0.f;
        #pragma unroll
        for (int j = lane; j < 160; j += 64)
            acc = fma4s(Wf[j], shf[j], acc);
        acc = wave_reduce_sum(acc);
        if (lane == 0) h1[n * 64 + k] = fmaxf(acc + b1[n * 64 + k], 0.f);
    } else {
        // ---- M + y0 partials: node n, rows i0..i0+31 (R9-verified) ----
        const int t  = b - 432;
        const int n  = t / 10;
        const int i0 = (t % 10) * 32;
        float4* shf = reinterpret_cast<float4*>(sh);
        const float4* __restrict__ s1f = reinterpret_cast<const float4*>(states1) + (size_t)n * 80;
        const float4* __restrict__ b2f = reinterpret_cast<const float4*>(b2) + (size_t)n * 80;
        if (tid < 80) shf[tid] = add4(s1f[tid], b2f[tid]);
        __syncthreads();

        const int r0 = i0 + wv * 8;     // this wave's 8 rows (0..319)
        const float* __restrict__ W2n = W2 + (size_t)n * 320 * 64;
        float accm[8];
        #pragma unroll
        for (int rr = 0; rr < 8; ++rr) accm[rr] = 0.f;

        #pragma unroll 2
        for (int j = 0; j < 320; ++j) {
            float w2 = W2n[(size_t)j * 64 + lane];          // coalesced
            #pragma unroll
            for (int rr = 0; rr < 8; ++rr) {
                float w0 = aggW0[(size_t)(r0 + rr) * 8640 + n * 320 + j];  // uniform
                accm[rr] = fmaf(w0, w2, accm[rr]);
            }
        }
        #pragma unroll
        for (int rr = 0; rr < 8; ++rr)
            M[(size_t)(r0 + rr) * 1728 + n * 64 + lane] = accm[rr];

        // y0 partial for the same rows (W0 slice L1-hot)
        #pragma unroll
        for (int rr = 0; rr < 8; ++rr) {
            const int r = r0 + rr;
            float yv = 0.f;
            #pragma unroll
            for (int m = 0; m < 5; ++m) {
                int j = lane + 64 * m;
                yv = fmaf(aggW0[(size_t)r * 8640 + n * 320 + j], sh[j], yv);
            }
            yv = wave_reduce_sum(yv);
            if (lane == 0) y0p[n * 320 + r] = yv;
        }
    }
}

// ---------------------------------------------------------------------------
// K3: agg0[i] = sum_n y0p[n][i] + agg_b0[i] + M[i,:] @ h1. 80 blocks x 4 rows.
__global__ void __launch_bounds__(256) K3(
    const float* __restrict__ M,      // ws [320][1728]
    const float* __restrict__ h1,     // ws [1728]
    const float* __restrict__ y0p,    // ws [27][320]
    const float* __restrict__ aggb0,  // [320]
    float*       __restrict__ agg0)   // ws [320]
{
    __shared__ __align__(16) float hs[1728];
    const int tid = threadIdx.x;
    const int wv  = tid >> 6, lane = tid & 63;

    float4* hsf = reinterpret_cast<float4*>(hs);
    const float4* __restrict__ h1f = reinterpret_cast<const float4*>(h1);
    for (int j = tid; j < 432; j += 256) hsf[j] = h1f[j];
    __syncthreads();

    const int i = blockIdx.x * 4 + wv;   // 0..319
    const float4* __restrict__ Mf = reinterpret_cast<const float4*>(M) + (size_t)i * 432;
    float acc = 0.f;
    for (int j = lane; j < 432; j += 64)
        acc = fma4s(Mf[j], hsf[j], acc);
    if (lane < 27) acc += y0p[lane * 320 + i];
    acc = wave_reduce_sum(acc);
    if (lane == 0) agg0[i] = acc + aggb0[i];
}

// ---------------------------------------------------------------------------
// K4: root MLP, 80 blocks; each block recomputes h0 (L2-hot 160 KB), then 4 rows.
__global__ void __launch_bounds__(256) K4(
    const float* __restrict__ state0,  // [320]
    const float* __restrict__ ext,     // [320]
    const float* __restrict__ agg0,    // ws [320]
    const float* __restrict__ W1,      // up_W1_0 [64][640]
    const float* __restrict__ b1,      // [64]
    const float* __restrict__ W2,      // up_W2_0 [320][64]
    const float* __restrict__ b2,      // [320]
    float*       __restrict__ out)     // [320]
{
    __shared__ __align__(16) float comb[640];
    __shared__ float h[64];
    const int tid = threadIdx.x;
    const int wv  = tid >> 6, lane = tid & 63;

    float4* combf = reinterpret_cast<float4*>(comb);
    const float4* __restrict__ s0f = reinterpret_cast<const float4*>(state0);
    const float4* __restrict__ exf = reinterpret_cast<const float4*>(ext);
    const float4* __restrict__ agf = reinterpret_cast<const float4*>(agg0);
    if (tid < 80)       combf[tid] = add4(s0f[tid], exf[tid]);
    else if (tid < 160) combf[tid] = agf[tid - 80];
    __syncthreads();

    const float4* __restrict__ cf = reinterpret_cast<const float4*>(comb);
    for (int kk = 0; kk < 16; ++kk) {
        const int k = wv * 16 + kk;
        const float4* __restrict__ Wf = reinterpret_cast<const float4*>(W1) + (size_t)k * 160;
        float acc = 0.f;
        for (int j = lane; j < 160; j += 64)
            acc = fma4s(Wf[j], cf[j], acc);
        acc = wave_reduce_sum(acc);
        if (lane == 0) h[k] = fmaxf(acc + b1[k], 0.f);
    }
    __syncthreads();

    const int i = blockIdx.x * 4 + wv;   // 0..319
    float acc = W2[(size_t)i * 64 + lane] * h[lane];
    acc = wave_reduce_sum(acc);
    if (lane == 0) out[i] = comb[i] + acc + b2[i];
}

extern "C" void kernel_launch(void* const* d_in, const int* in_sizes, int n_in,
                              void* d_out, int out_size, void* d_ws, size_t ws_size,
                              hipStream_t stream) {
    const float* ext      = (const float*)d_in[0];
    const float* state0   = (const float*)d_in[1];
    const float* states1  = (const float*)d_in[2];
    const float* states2  = (const float*)d_in[3];
    const float* agg_W0   = (const float*)d_in[4];
    const float* agg_b0   = (const float*)d_in[5];
    const float* agg_W1   = (const float*)d_in[6];
    const float* agg_b1   = (const float*)d_in[7];
    const float* up_W1_0  = (const float*)d_in[8];
    const float* up_b1_0  = (const float*)d_in[9];
    const float* up_W2_0  = (const float*)d_in[10];
    const float* up_b2_0  = (const float*)d_in[11];
    const float* up_W1_1  = (const float*)d_in[12];
    const float* up_b1_1  = (const float*)d_in[13];
    const float* up_W2_1  = (const float*)d_in[14];
    const float* up_b2_1  = (const float*)d_in[15];

    float* out  = (float*)d_out;
    float* ws   = (float*)d_ws;
    float* agg1 = ws;              // 8640
    float* h1   = ws + 8640;       // 1728
    float* y0p  = ws + 10368;      // 8640
    float* agg0 = ws + 19008;      // 320
    float* M    = ws + 19328;      // 552960 (2.2 MB)

    k1_gemv<<<1080, 256, 0, stream>>>(agg_W1, states2, agg_b1, agg1);
    K2<<<702, 256, 0, stream>>>(states1, agg1, up_W1_1, up_b1_1, up_W2_1, up_b2_1,
                                agg_W0, h1, y0p, M);
    K3<<<80, 256, 0, stream>>>(M, h1, y0p, agg_b0, agg0);
    K4<<<80, 256, 0, stream>>>(state0, ext, agg0, up_W1_0, up_b1_0, up_W2_0, up_b2_0, out);
}

// Round 11
// 83.289 us; speedup vs baseline: 1.9638x; 1.9638x over previous
//
#include <hip/hip_runtime.h>
#include <hip/hip_bf16.h>

// S=64, C=27. DOTLEN = 8640 floats = 2160 float4/row; state = 320; comb = 640; hidden = 64.
// R4 champion structure (69.1 us), with k4a+k4b merged into one 80-block K4.

__device__ __forceinline__ float wave_reduce_sum(float v) {
    v += __shfl_xor(v, 32, 64);
    v += __shfl_xor(v, 16, 64);
    v += __shfl_xor(v, 8, 64);
    v += __shfl_xor(v, 4, 64);
    v += __shfl_xor(v, 2, 64);
    v += __shfl_xor(v, 1, 64);
    return v;
}

__device__ __forceinline__ float fma4s(float4 w, float4 x, float acc) {
    acc = fmaf(w.x, x.x, acc);
    acc = fmaf(w.y, x.y, acc);
    acc = fmaf(w.z, x.z, acc);
    acc = fmaf(w.w, x.w, acc);
    return acc;
}

__device__ __forceinline__ float4 add4(float4 a, float4 b) {
    return make_float4(a.x + b.x, a.y + b.y, a.z + b.z, a.w + b.w);
}

// ---------------------------------------------------------------------------
// k1: agg1[8640] = agg_W1 . leaf_flat + agg_b1. (R4 exact: 4 rows/block,
// column-parallel, 2160 blocks)
__global__ void __launch_bounds__(256) k1_gemv(
    const float* __restrict__ W,     // [8640][8640] block-diag rows
    const float* __restrict__ x,     // [27][8640]
    const float* __restrict__ bias,  // [8640]
    float*       __restrict__ y)     // [8640]
{
    const int b    = blockIdx.x;
    const int node = b / 80;
    const int row0 = node * 320 + (b % 80) * 4;
    const int tid  = threadIdx.x;

    const float4* __restrict__ xf  = reinterpret_cast<const float4*>(x) + (size_t)node * 2160;
    const float4* __restrict__ w0p = reinterpret_cast<const float4*>(W) + (size_t)(row0 + 0) * 2160;
    const float4* __restrict__ w1p = reinterpret_cast<const float4*>(W) + (size_t)(row0 + 1) * 2160;
    const float4* __restrict__ w2p = reinterpret_cast<const float4*>(W) + (size_t)(row0 + 2) * 2160;
    const float4* __restrict__ w3p = reinterpret_cast<const float4*>(W) + (size_t)(row0 + 3) * 2160;

    float4 a0 = make_float4(0.f, 0.f, 0.f, 0.f), a1 = a0, a2 = a0, a3 = a0;
    for (int j = tid; j < 2160; j += 256) {
        float4 xv = xf[j];
        float4 w0 = w0p[j];
        float4 w1 = w1p[j];
        float4 w2 = w2p[j];
        float4 w3 = w3p[j];
        a0.x = fmaf(w0.x, xv.x, a0.x); a0.y = fmaf(w0.y, xv.y, a0.y);
        a0.z = fmaf(w0.z, xv.z, a0.z); a0.w = fmaf(w0.w, xv.w, a0.w);
        a1.x = fmaf(w1.x, xv.x, a1.x); a1.y = fmaf(w1.y, xv.y, a1.y);
        a1.z = fmaf(w1.z, xv.z, a1.z); a1.w = fmaf(w1.w, xv.w, a1.w);
        a2.x = fmaf(w2.x, xv.x, a2.x); a2.y = fmaf(w2.y, xv.y, a2.y);
        a2.z = fmaf(w2.z, xv.z, a2.z); a2.w = fmaf(w2.w, xv.w, a2.w);
        a3.x = fmaf(w3.x, xv.x, a3.x); a3.y = fmaf(w3.y, xv.y, a3.y);
        a3.z = fmaf(w3.z, xv.z, a3.z); a3.w = fmaf(w3.w, xv.w, a3.w);
    }
    float s0 = (a0.x + a0.y) + (a0.z + a0.w);
    float s1 = (a1.x + a1.y) + (a1.z + a1.w);
    float s2 = (a2.x + a2.y) + (a2.z + a2.w);
    float s3 = (a3.x + a3.y) + (a3.z + a3.w);
    s0 = wave_reduce_sum(s0);
    s1 = wave_reduce_sum(s1);
    s2 = wave_reduce_sum(s2);
    s3 = wave_reduce_sum(s3);

    __shared__ float red[4][4];
    const int wv = tid >> 6, lane = tid & 63;
    if (lane == 0) { red[wv][0] = s0; red[wv][1] = s1; red[wv][2] = s2; red[wv][3] = s3; }
    __syncthreads();
    if (tid < 4) {
        float v = red[0][tid] + red[1][tid] + red[2][tid] + red[3][tid];
        y[row0 + tid] = v + bias[row0 + tid];
    }
}

// ---------------------------------------------------------------------------
// k2a: h1[27][64] = relu(up_W1_1 @ comb1 + b1). (R4 exact, 432 blocks)
__global__ void __launch_bounds__(256) k2a_h(
    const float* __restrict__ states1,  // [27][320]
    const float* __restrict__ agg1,     // [8640] (ws)
    const float* __restrict__ W1,       // [27][64][640]
    const float* __restrict__ b1,       // [27][64]
    float*       __restrict__ h1)       // [27][64] (ws)
{
    __shared__ float comb[640];
    const int nb  = blockIdx.x;
    const int n   = nb / 16;
    const int tid = threadIdx.x;

    float4* combf = reinterpret_cast<float4*>(comb);
    const float4* __restrict__ s1f = reinterpret_cast<const float4*>(states1) + (size_t)n * 80;
    const float4* __restrict__ a1f = reinterpret_cast<const float4*>(agg1) + (size_t)n * 80;
    if (tid < 80)       combf[tid] = s1f[tid];
    else if (tid < 160) combf[tid] = a1f[tid - 80];
    __syncthreads();

    const int wv = tid >> 6, lane = tid & 63;
    const int k  = (nb % 16) * 4 + wv;
    const float4* __restrict__ Wf = reinterpret_cast<const float4*>(W1) + ((size_t)n * 64 + k) * 160;
    float acc = 0.f;
    #pragma unroll
    for (int j = lane; j < 160; j += 64)
        acc = fma4s(Wf[j], combf[j], acc);
    acc = wave_reduce_sum(acc);
    if (lane == 0) h1[n * 64 + k] = fmaxf(acc + b1[n * 64 + k], 0.f);
}

// ---------------------------------------------------------------------------
// k2b: ns1[8640] = states1 + up_W2_1 @ h1 + b2. (R4 exact, 2160 blocks)
__global__ void __launch_bounds__(256) k2b_ns(
    const float* __restrict__ states1,  // [8640]
    const float* __restrict__ h1,       // [27][64] (ws)
    const float* __restrict__ W2,       // [8640][64]
    const float* __restrict__ b2,       // [8640]
    float*       __restrict__ ns1)      // [8640] (ws)
{
    const int tid  = threadIdx.x;
    const int wv   = tid >> 6, lane = tid & 63;
    const int i    = blockIdx.x * 4 + wv;   // 0..8639
    const int n    = i / 320;
    float acc = W2[(size_t)i * 64 + lane] * h1[n * 64 + lane];
    acc = wave_reduce_sum(acc);
    if (lane == 0) ns1[i] = states1[i] + acc + b2[i];
}

// ---------------------------------------------------------------------------
// k3: agg0 partials: agg0p[cs][320]. (R4 exact, 320 blocks)
__global__ void __launch_bounds__(256) k3_gemv(
    const float* __restrict__ W,    // [320][8640]
    const float* __restrict__ x,    // ns1 [8640] (ws)
    float*       __restrict__ yp)   // [4][320] partials (ws)
{
    const int b   = blockIdx.x;     // 0..319
    const int cs  = b / 80;
    const int r0  = (b % 80) * 4;
    const int tid = threadIdx.x;

    const float4* __restrict__ xf  = reinterpret_cast<const float4*>(x);
    const float4* __restrict__ w0p = reinterpret_cast<const float4*>(W) + (size_t)(r0 + 0) * 2160;
    const float4* __restrict__ w1p = reinterpret_cast<const float4*>(W) + (size_t)(r0 + 1) * 2160;
    const float4* __restrict__ w2p = reinterpret_cast<const float4*>(W) + (size_t)(r0 + 2) * 2160;
    const float4* __restrict__ w3p = reinterpret_cast<const float4*>(W) + (size_t)(r0 + 3) * 2160;

    float4 a0 = make_float4(0.f, 0.f, 0.f, 0.f), a1 = a0, a2 = a0, a3 = a0;
    const int jend = cs * 540 + 540;
    for (int j = cs * 540 + tid; j < jend; j += 256) {
        float4 xv = xf[j];
        float4 w0 = w0p[j];
        float4 w1 = w1p[j];
        float4 w2 = w2p[j];
        float4 w3 = w3p[j];
        a0.x = fmaf(w0.x, xv.x, a0.x); a0.y = fmaf(w0.y, xv.y, a0.y);
        a0.z = fmaf(w0.z, xv.z, a0.z); a0.w = fmaf(w0.w, xv.w, a0.w);
        a1.x = fmaf(w1.x, xv.x, a1.x); a1.y = fmaf(w1.y, xv.y, a1.y);
        a1.z = fmaf(w1.z, xv.z, a1.z); a1.w = fmaf(w1.w, xv.w, a1.w);
        a2.x = fmaf(w2.x, xv.x, a2.x); a2.y = fmaf(w2.y, xv.y, a2.y);
        a2.z = fmaf(w2.z, xv.z, a2.z); a2.w = fmaf(w2.w, xv.w, a2.w);
        a3.x = fmaf(w3.x, xv.x, a3.x); a3.y = fmaf(w3.y, xv.y, a3.y);
        a3.z = fmaf(w3.z, xv.z, a3.z); a3.w = fmaf(w3.w, xv.w, a3.w);
    }
    float s0 = (a0.x + a0.y) + (a0.z + a0.w);
    float s1 = (a1.x + a1.y) + (a1.z + a1.w);
    float s2 = (a2.x + a2.y) + (a2.z + a2.w);
    float s3 = (a3.x + a3.y) + (a3.z + a3.w);
    s0 = wave_reduce_sum(s0);
    s1 = wave_reduce_sum(s1);
    s2 = wave_reduce_sum(s2);
    s3 = wave_reduce_sum(s3);

    __shared__ float red[4][4];
    const int wv = tid >> 6, lane = tid & 63;
    if (lane == 0) { red[wv][0] = s0; red[wv][1] = s1; red[wv][2] = s2; red[wv][3] = s3; }
    __syncthreads();
    if (tid < 4) {
        yp[cs * 320 + r0 + tid] =
            red[0][tid] + red[1][tid] + red[2][tid] + red[3][tid];
    }
}

// ---------------------------------------------------------------------------
// K4: merged root MLP (k4a+k4b). 80 blocks; each block sums agg0 partials,
// recomputes h0 (L2-hot W1_0), writes its 4 output rows.
__global__ void __launch_bounds__(256) K4_root(
    const float* __restrict__ state0,  // [320]
    const float* __restrict__ ext,     // [320]
    const float* __restrict__ agg0p,   // [4][320] (ws)
    const float* __restrict__ aggb0,   // [320]
    const float* __restrict__ W1,      // up_W1_0 [64][640]
    const float* __restrict__ b1,      // [64]
    const float* __restrict__ W2,      // up_W2_0 [320][64]
    const float* __restrict__ b2,      // [320]
    float*       __restrict__ out)     // [320]
{
    __shared__ __align__(16) float comb[640];
    __shared__ float h[64];
    const int tid = threadIdx.x;
    const int wv  = tid >> 6, lane = tid & 63;

    float4* combf = reinterpret_cast<float4*>(comb);
    const float4* __restrict__ s0f = reinterpret_cast<const float4*>(state0);
    const float4* __restrict__ exf = reinterpret_cast<const float4*>(ext);
    const float4* __restrict__ p0  = reinterpret_cast<const float4*>(agg0p);
    const float4* __restrict__ b0f = reinterpret_cast<const float4*>(aggb0);
    if (tid < 80) {
        combf[tid] = add4(s0f[tid], exf[tid]);
    } else if (tid < 160) {
        int jj = tid - 80;
        combf[tid] = add4(add4(add4(p0[jj], p0[80 + jj]), add4(p0[160 + jj], p0[240 + jj])), b0f[jj]);
    }
    __syncthreads();

    const float4* __restrict__ cf = reinterpret_cast<const float4*>(comb);
    for (int kk = 0; kk < 16; ++kk) {
        const int k = wv * 16 + kk;
        const float4* __restrict__ Wf = reinterpret_cast<const float4*>(W1) + (size_t)k * 160;
        float acc = 0.f;
        for (int j = lane; j < 160; j += 64)
            acc = fma4s(Wf[j], cf[j], acc);
        acc = wave_reduce_sum(acc);
        if (lane == 0) h[k] = fmaxf(acc + b1[k], 0.f);
    }
    __syncthreads();

    const int i = blockIdx.x * 4 + wv;   // 0..319
    float acc = W2[(size_t)i * 64 + lane] * h[lane];
    acc = wave_reduce_sum(acc);
    if (lane == 0) out[i] = comb[i] + acc + b2[i];
}

extern "C" void kernel_launch(void* const* d_in, const int* in_sizes, int n_in,
                              void* d_out, int out_size, void* d_ws, size_t ws_size,
                              hipStream_t stream) {
    const float* ext      = (const float*)d_in[0];
    const float* state0   = (const float*)d_in[1];
    const float* states1  = (const float*)d_in[2];
    const float* states2  = (const float*)d_in[3];
    const float* agg_W0   = (const float*)d_in[4];
    const float* agg_b0   = (const float*)d_in[5];
    const float* agg_W1   = (const float*)d_in[6];
    const float* agg_b1   = (const float*)d_in[7];
    const float* up_W1_0  = (const float*)d_in[8];
    const float* up_b1_0  = (const float*)d_in[9];
    const float* up_W2_0  = (const float*)d_in[10];
    const float* up_b2_0  = (const float*)d_in[11];
    const float* up_W1_1  = (const float*)d_in[12];
    const float* up_b1_1  = (const float*)d_in[13];
    const float* up_W2_1  = (const float*)d_in[14];
    const float* up_b2_1  = (const float*)d_in[15];

    float* out   = (float*)d_out;
    float* ws    = (float*)d_ws;
    float* agg1  = ws;             // 8640
    float* h1    = ws + 8640;      // 1728
    float* ns1   = ws + 10368;     // 8640
    float* agg0p = ws + 19008;     // 1280

    k1_gemv<<<2160, 256, 0, stream>>>(agg_W1, states2, agg_b1, agg1);
    k2a_h  <<<432,  256, 0, stream>>>(states1, agg1, up_W1_1, up_b1_1, h1);
    k2b_ns <<<2160, 256, 0, stream>>>(states1, h1, up_W2_1, up_b2_1, ns1);
    k3_gemv<<<320,  256, 0, stream>>>(agg_W0, ns1, agg0p);
    K4_root<<<80,   256, 0, stream>>>(state0, ext, agg0p, agg_b0,
                                      up_W1_0, up_b1_0, up_W2_0, up_b2_0, out);
}

// Round 12
// 68.608 us; speedup vs baseline: 2.3841x; 1.2140x over previous
//
#include <hip/hip_runtime.h>
#include <hip/hip_bf16.h>

// S=64, C=27. DOTLEN = 8640 floats = 2160 float4/row; state = 320; comb = 640; hidden = 64.
// R4 champion structure (69.1 us) with ONE change: k1's j-loop manually
// 2-way unrolled (10 independent loads in flight vs 5) to test issue-depth.

__device__ __forceinline__ float wave_reduce_sum(float v) {
    v += __shfl_xor(v, 32, 64);
    v += __shfl_xor(v, 16, 64);
    v += __shfl_xor(v, 8, 64);
    v += __shfl_xor(v, 4, 64);
    v += __shfl_xor(v, 2, 64);
    v += __shfl_xor(v, 1, 64);
    return v;
}

__device__ __forceinline__ float fma4s(float4 w, float4 x, float acc) {
    acc = fmaf(w.x, x.x, acc);
    acc = fmaf(w.y, x.y, acc);
    acc = fmaf(w.z, x.z, acc);
    acc = fmaf(w.w, x.w, acc);
    return acc;
}

__device__ __forceinline__ float4 add4(float4 a, float4 b) {
    return make_float4(a.x + b.x, a.y + b.y, a.z + b.z, a.w + b.w);
}

// ---------------------------------------------------------------------------
// k1: agg1[8640] = agg_W1 . leaf_flat + agg_b1. 4 rows/block, column-parallel,
// 2160 blocks. j-loop 2-way unrolled: each main iteration issues 2 x-loads +
// 8 W-loads (all independent) before any FMA consumes them.
__global__ void __launch_bounds__(256) k1_gemv(
    const float* __restrict__ W,     // [8640][8640] block-diag rows
    const float* __restrict__ x,     // [27][8640]
    const float* __restrict__ bias,  // [8640]
    float*       __restrict__ y)     // [8640]
{
    const int b    = blockIdx.x;
    const int node = b / 80;
    const int row0 = node * 320 + (b % 80) * 4;
    const int tid  = threadIdx.x;

    const float4* __restrict__ xf  = reinterpret_cast<const float4*>(x) + (size_t)node * 2160;
    const float4* __restrict__ w0p = reinterpret_cast<const float4*>(W) + (size_t)(row0 + 0) * 2160;
    const float4* __restrict__ w1p = reinterpret_cast<const float4*>(W) + (size_t)(row0 + 1) * 2160;
    const float4* __restrict__ w2p = reinterpret_cast<const float4*>(W) + (size_t)(row0 + 2) * 2160;
    const float4* __restrict__ w3p = reinterpret_cast<const float4*>(W) + (size_t)(row0 + 3) * 2160;

    float4 a0 = make_float4(0.f, 0.f, 0.f, 0.f), a1 = a0, a2 = a0, a3 = a0;
    float4 c0 = a0, c1 = a0, c2 = a0, c3 = a0;   // second accumulator set

    int j = tid;
    for (; j + 256 < 2160; j += 512) {
        const int j2 = j + 256;
        float4 xv  = xf[j];
        float4 w0  = w0p[j];
        float4 w1  = w1p[j];
        float4 w2  = w2p[j];
        float4 w3  = w3p[j];
        float4 xv2 = xf[j2];
        float4 u0  = w0p[j2];
        float4 u1  = w1p[j2];
        float4 u2  = w2p[j2];
        float4 u3  = w3p[j2];
        a0.x = fmaf(w0.x, xv.x, a0.x); a0.y = fmaf(w0.y, xv.y, a0.y);
        a0.z = fmaf(w0.z, xv.z, a0.z); a0.w = fmaf(w0.w, xv.w, a0.w);
        a1.x = fmaf(w1.x, xv.x, a1.x); a1.y = fmaf(w1.y, xv.y, a1.y);
        a1.z = fmaf(w1.z, xv.z, a1.z); a1.w = fmaf(w1.w, xv.w, a1.w);
        a2.x = fmaf(w2.x, xv.x, a2.x); a2.y = fmaf(w2.y, xv.y, a2.y);
        a2.z = fmaf(w2.z, xv.z, a2.z); a2.w = fmaf(w2.w, xv.w, a2.w);
        a3.x = fmaf(w3.x, xv.x, a3.x); a3.y = fmaf(w3.y, xv.y, a3.y);
        a3.z = fmaf(w3.z, xv.z, a3.z); a3.w = fmaf(w3.w, xv.w, a3.w);
        c0.x = fmaf(u0.x, xv2.x, c0.x); c0.y = fmaf(u0.y, xv2.y, c0.y);
        c0.z = fmaf(u0.z, xv2.z, c0.z); c0.w = fmaf(u0.w, xv2.w, c0.w);
        c1.x = fmaf(u1.x, xv2.x, c1.x); c1.y = fmaf(u1.y, xv2.y, c1.y);
        c1.z = fmaf(u1.z, xv2.z, c1.z); c1.w = fmaf(u1.w, xv2.w, c1.w);
        c2.x = fmaf(u2.x, xv2.x, c2.x); c2.y = fmaf(u2.y, xv2.y, c2.y);
        c2.z = fmaf(u2.z, xv2.z, c2.z); c2.w = fmaf(u2.w, xv2.w, c2.w);
        c3.x = fmaf(u3.x, xv2.x, c3.x); c3.y = fmaf(u3.y, xv2.y, c3.y);
        c3.z = fmaf(u3.z, xv2.z, c3.z); c3.w = fmaf(u3.w, xv2.w, c3.w);
    }
    for (; j < 2160; j += 256) {
        float4 xv = xf[j];
        float4 w0 = w0p[j];
        float4 w1 = w1p[j];
        float4 w2 = w2p[j];
        float4 w3 = w3p[j];
        a0.x = fmaf(w0.x, xv.x, a0.x); a0.y = fmaf(w0.y, xv.y, a0.y);
        a0.z = fmaf(w0.z, xv.z, a0.z); a0.w = fmaf(w0.w, xv.w, a0.w);
        a1.x = fmaf(w1.x, xv.x, a1.x); a1.y = fmaf(w1.y, xv.y, a1.y);
        a1.z = fmaf(w1.z, xv.z, a1.z); a1.w = fmaf(w1.w, xv.w, a1.w);
        a2.x = fmaf(w2.x, xv.x, a2.x); a2.y = fmaf(w2.y, xv.y, a2.y);
        a2.z = fmaf(w2.z, xv.z, a2.z); a2.w = fmaf(w2.w, xv.w, a2.w);
        a3.x = fmaf(w3.x, xv.x, a3.x); a3.y = fmaf(w3.y, xv.y, a3.y);
        a3.z = fmaf(w3.z, xv.z, a3.z); a3.w = fmaf(w3.w, xv.w, a3.w);
    }
    a0 = add4(a0, c0); a1 = add4(a1, c1); a2 = add4(a2, c2); a3 = add4(a3, c3);

    float s0 = (a0.x + a0.y) + (a0.z + a0.w);
    float s1 = (a1.x + a1.y) + (a1.z + a1.w);
    float s2 = (a2.x + a2.y) + (a2.z + a2.w);
    float s3 = (a3.x + a3.y) + (a3.z + a3.w);
    s0 = wave_reduce_sum(s0);
    s1 = wave_reduce_sum(s1);
    s2 = wave_reduce_sum(s2);
    s3 = wave_reduce_sum(s3);

    __shared__ float red[4][4];
    const int wv = tid >> 6, lane = tid & 63;
    if (lane == 0) { red[wv][0] = s0; red[wv][1] = s1; red[wv][2] = s2; red[wv][3] = s3; }
    __syncthreads();
    if (tid < 4) {
        float v = red[0][tid] + red[1][tid] + red[2][tid] + red[3][tid];
        y[row0 + tid] = v + bias[row0 + tid];
    }
}

// ---------------------------------------------------------------------------
// k2a: h1[27][64] = relu(up_W1_1 @ comb1 + b1). (R4 exact, 432 blocks)
__global__ void __launch_bounds__(256) k2a_h(
    const float* __restrict__ states1,  // [27][320]
    const float* __restrict__ agg1,     // [8640] (ws)
    const float* __restrict__ W1,       // [27][64][640]
    const float* __restrict__ b1,       // [27][64]
    float*       __restrict__ h1)       // [27][64] (ws)
{
    __shared__ float comb[640];
    const int nb  = blockIdx.x;
    const int n   = nb / 16;
    const int tid = threadIdx.x;

    float4* combf = reinterpret_cast<float4*>(comb);
    const float4* __restrict__ s1f = reinterpret_cast<const float4*>(states1) + (size_t)n * 80;
    const float4* __restrict__ a1f = reinterpret_cast<const float4*>(agg1) + (size_t)n * 80;
    if (tid < 80)       combf[tid] = s1f[tid];
    else if (tid < 160) combf[tid] = a1f[tid - 80];
    __syncthreads();

    const int wv = tid >> 6, lane = tid & 63;
    const int k  = (nb % 16) * 4 + wv;
    const float4* __restrict__ Wf = reinterpret_cast<const float4*>(W1) + ((size_t)n * 64 + k) * 160;
    float acc = 0.f;
    #pragma unroll
    for (int j = lane; j < 160; j += 64)
        acc = fma4s(Wf[j], combf[j], acc);
    acc = wave_reduce_sum(acc);
    if (lane == 0) h1[n * 64 + k] = fmaxf(acc + b1[n * 64 + k], 0.f);
}

// ---------------------------------------------------------------------------
// k2b: ns1[8640] = states1 + up_W2_1 @ h1 + b2. (R4 exact, 2160 blocks)
__global__ void __launch_bounds__(256) k2b_ns(
    const float* __restrict__ states1,  // [8640]
    const float* __restrict__ h1,       // [27][64] (ws)
    const float* __restrict__ W2,       // [8640][64]
    const float* __restrict__ b2,       // [8640]
    float*       __restrict__ ns1)      // [8640] (ws)
{
    const int tid  = threadIdx.x;
    const int wv   = tid >> 6, lane = tid & 63;
    const int i    = blockIdx.x * 4 + wv;   // 0..8639
    const int n    = i / 320;
    float acc = W2[(size_t)i * 64 + lane] * h1[n * 64 + lane];
    acc = wave_reduce_sum(acc);
    if (lane == 0) ns1[i] = states1[i] + acc + b2[i];
}

// ---------------------------------------------------------------------------
// k3: agg0 partials: agg0p[cs][320]. (R4 exact, 320 blocks)
__global__ void __launch_bounds__(256) k3_gemv(
    const float* __restrict__ W,    // [320][8640]
    const float* __restrict__ x,    // ns1 [8640] (ws)
    float*       __restrict__ yp)   // [4][320] partials (ws)
{
    const int b   = blockIdx.x;     // 0..319
    const int cs  = b / 80;
    const int r0  = (b % 80) * 4;
    const int tid = threadIdx.x;

    const float4* __restrict__ xf  = reinterpret_cast<const float4*>(x);
    const float4* __restrict__ w0p = reinterpret_cast<const float4*>(W) + (size_t)(r0 + 0) * 2160;
    const float4* __restrict__ w1p = reinterpret_cast<const float4*>(W) + (size_t)(r0 + 1) * 2160;
    const float4* __restrict__ w2p = reinterpret_cast<const float4*>(W) + (size_t)(r0 + 2) * 2160;
    const float4* __restrict__ w3p = reinterpret_cast<const float4*>(W) + (size_t)(r0 + 3) * 2160;

    float4 a0 = make_float4(0.f, 0.f, 0.f, 0.f), a1 = a0, a2 = a0, a3 = a0;
    const int jend = cs * 540 + 540;
    for (int j = cs * 540 + tid; j < jend; j += 256) {
        float4 xv = xf[j];
        float4 w0 = w0p[j];
        float4 w1 = w1p[j];
        float4 w2 = w2p[j];
        float4 w3 = w3p[j];
        a0.x = fmaf(w0.x, xv.x, a0.x); a0.y = fmaf(w0.y, xv.y, a0.y);
        a0.z = fmaf(w0.z, xv.z, a0.z); a0.w = fmaf(w0.w, xv.w, a0.w);
        a1.x = fmaf(w1.x, xv.x, a1.x); a1.y = fmaf(w1.y, xv.y, a1.y);
        a1.z = fmaf(w1.z, xv.z, a1.z); a1.w = fmaf(w1.w, xv.w, a1.w);
        a2.x = fmaf(w2.x, xv.x, a2.x); a2.y = fmaf(w2.y, xv.y, a2.y);
        a2.z = fmaf(w2.z, xv.z, a2.z); a2.w = fmaf(w2.w, xv.w, a2.w);
        a3.x = fmaf(w3.x, xv.x, a3.x); a3.y = fmaf(w3.y, xv.y, a3.y);
        a3.z = fmaf(w3.z, xv.z, a3.z); a3.w = fmaf(w3.w, xv.w, a3.w);
    }
    float s0 = (a0.x + a0.y) + (a0.z + a0.w);
    float s1 = (a1.x + a1.y) + (a1.z + a1.w);
    float s2 = (a2.x + a2.y) + (a2.z + a2.w);
    float s3 = (a3.x + a3.y) + (a3.z + a3.w);
    s0 = wave_reduce_sum(s0);
    s1 = wave_reduce_sum(s1);
    s2 = wave_reduce_sum(s2);
    s3 = wave_reduce_sum(s3);

    __shared__ float red[4][4];
    const int wv = tid >> 6, lane = tid & 63;
    if (lane == 0) { red[wv][0] = s0; red[wv][1] = s1; red[wv][2] = s2; red[wv][3] = s3; }
    __syncthreads();
    if (tid < 4) {
        yp[cs * 320 + r0 + tid] =
            red[0][tid] + red[1][tid] + red[2][tid] + red[3][tid];
    }
}

// ---------------------------------------------------------------------------
// k4a: h0[64] = relu(up_W1_0 @ comb0 + b1_0). (R4 exact, 16 blocks)
__global__ void __launch_bounds__(256) k4a_h(
    const float* __restrict__ state0,  // [320]
    const float* __restrict__ ext,     // [320]
    const float* __restrict__ agg0p,   // [4][320] (ws)
    const float* __restrict__ agg_b0,  // [320]
    const float* __restrict__ W1,      // [64][640]
    const float* __restrict__ b1,      // [64]
    float*       __restrict__ h0)      // [64] (ws)
{
    __shared__ float comb[640];
    const int tid = threadIdx.x;
    float4* combf = reinterpret_cast<float4*>(comb);
    const float4* __restrict__ s0f = reinterpret_cast<const float4*>(state0);
    const float4* __restrict__ exf = reinterpret_cast<const float4*>(ext);
    const float4* __restrict__ p0  = reinterpret_cast<const float4*>(agg0p);
    const float4* __restrict__ p1  = p0 + 80;
    const float4* __restrict__ p2  = p0 + 160;
    const float4* __restrict__ p3  = p0 + 240;
    const float4* __restrict__ b0f = reinterpret_cast<const float4*>(agg_b0);
    if (tid < 80) {
        combf[tid] = add4(s0f[tid], exf[tid]);
    } else if (tid < 160) {
        int jj = tid - 80;
        combf[tid] = add4(add4(add4(p0[jj], p1[jj]), add4(p2[jj], p3[jj])), b0f[jj]);
    }
    __syncthreads();

    const int wv = tid >> 6, lane = tid & 63;
    const int k  = blockIdx.x * 4 + wv;     // 0..63
    const float4* __restrict__ Wf = reinterpret_cast<const float4*>(W1) + (size_t)k * 160;
    float acc = 0.f;
    #pragma unroll
    for (int j = lane; j < 160; j += 64)
        acc = fma4s(Wf[j], combf[j], acc);
    acc = wave_reduce_sum(acc);
    if (lane == 0) h0[k] = fmaxf(acc + b1[k], 0.f);
}

// ---------------------------------------------------------------------------
// k4b: out[320] = (state0+ext) + up_W2_0 @ h0 + b2_0. (R4 exact, 80 blocks)
__global__ void __launch_bounds__(256) k4b_out(
    const float* __restrict__ state0,  // [320]
    const float* __restrict__ ext,     // [320]
    const float* __restrict__ h0,      // [64] (ws)
    const float* __restrict__ W2,      // [320][64]
    const float* __restrict__ b2,      // [320]
    float*       __restrict__ out)     // [320]
{
    const int tid  = threadIdx.x;
    const int wv   = tid >> 6, lane = tid & 63;
    const int i    = blockIdx.x * 4 + wv;   // 0..319
    float acc = W2[(size_t)i * 64 + lane] * h0[lane];
    acc = wave_reduce_sum(acc);
    if (lane == 0) out[i] = state0[i] + ext[i] + acc + b2[i];
}

extern "C" void kernel_launch(void* const* d_in, const int* in_sizes, int n_in,
                              void* d_out, int out_size, void* d_ws, size_t ws_size,
                              hipStream_t stream) {
    const float* ext      = (const float*)d_in[0];
    const float* state0   = (const float*)d_in[1];
    const float* states1  = (const float*)d_in[2];
    const float* states2  = (const float*)d_in[3];
    const float* agg_W0   = (const float*)d_in[4];
    const float* agg_b0   = (const float*)d_in[5];
    const float* agg_W1   = (const float*)d_in[6];
    const float* agg_b1   = (const float*)d_in[7];
    const float* up_W1_0  = (const float*)d_in[8];
    const float* up_b1_0  = (const float*)d_in[9];
    const float* up_W2_0  = (const float*)d_in[10];
    const float* up_b2_0  = (const float*)d_in[11];
    const float* up_W1_1  = (const float*)d_in[12];
    const float* up_b1_1  = (const float*)d_in[13];
    const float* up_W2_1  = (const float*)d_in[14];
    const float* up_b2_1  = (const float*)d_in[15];

    float* out   = (float*)d_out;
    float* ws    = (float*)d_ws;
    float* agg1  = ws;             // 8640
    float* h1    = ws + 8640;      // 1728
    float* ns1   = ws + 10368;     // 8640
    float* agg0p = ws + 19008;     // 1280
    float* h0    = ws + 20288;     // 64

    k1_gemv<<<2160, 256, 0, stream>>>(agg_W1, states2, agg_b1, agg1);
    k2a_h  <<<432,  256, 0, stream>>>(states1, agg1, up_W1_1, up_b1_1, h1);
    k2b_ns <<<2160, 256, 0, stream>>>(states1, h1, up_W2_1, up_b2_1, ns1);
    k3_gemv<<<320,  256, 0, stream>>>(agg_W0, ns1, agg0p);
    k4a_h  <<<16,   256, 0, stream>>>(state0, ext, agg0p, agg_b0, up_W1_0, up_b1_0, h0);
    k4b_out<<<80,   256, 0, stream>>>(state0, ext, h0, up_W2_0, up_b2_0, out);
}